// Round 17
// baseline (739.335 us; speedup 1.0000x reference)
//
#include <hip/hip_runtime.h>
#include <hip/hip_bf16.h>
#include <stdint.h>

#define SQ 2048
#define DK 64
#define NB 32
#define SCL 0.18033688011112042f   // log2(e)/8

typedef __attribute__((ext_vector_type(8))) short short8;
typedef __attribute__((ext_vector_type(4))) float f32x4;
typedef __attribute__((ext_vector_type(4))) unsigned u32x4;
typedef __attribute__((ext_vector_type(2))) unsigned u32x2;

// ---- bf16 helpers ----
__device__ __forceinline__ unsigned f2bf_u(float x) {
    unsigned u = __builtin_bit_cast(unsigned, x);
    u += 0x7fffu + ((u >> 16) & 1u);
    return u >> 16;
}
__device__ __forceinline__ float bf2f(unsigned h) {
    return __builtin_bit_cast(float, h << 16);
}
__device__ __forceinline__ unsigned cvtpk_bf16(float lo, float hi) {
    unsigned r;
    asm("v_cvt_pk_bf16_f32 %0, %1, %2" : "=v"(r) : "v"(lo), "v"(hi));
    return r;
}
__device__ __forceinline__ void split8(const float* p, short8& h, short8& l) {
    f32x4 a = *(const f32x4*)p;
    f32x4 b = *(const f32x4*)(p + 4);
    #pragma unroll
    for (int j = 0; j < 4; ++j) {
        unsigned ua = f2bf_u(a[j]);
        h[j] = (short)ua; l[j] = (short)f2bf_u(a[j] - bf2f(ua));
        unsigned ub = f2bf_u(b[j]);
        h[j + 4] = (short)ub; l[j + 4] = (short)f2bf_u(b[j] - bf2f(ub));
    }
}

// ============ prep1: K -> bf16 hi/lo planes; V -> transposed bf16 plane ============
__global__ __launch_bounds__(256) void prep_kernel(
    const float* __restrict__ K, const float* __restrict__ V,
    unsigned short* __restrict__ Khi, unsigned short* __restrict__ Klo,
    unsigned short* __restrict__ Vt)
{
    __shared__ float vtile[64][65];
    const int t  = threadIdx.x;
    const int b  = blockIdx.x >> 5;
    const int s0 = (blockIdx.x & 31) << 6;
    const size_t base = ((size_t)b * SQ + s0) * DK + (size_t)t * 16;

    {
        short8 h0, l0, h1, l1;
        split8(K + base,     h0, l0);
        split8(K + base + 8, h1, l1);
        *(short8*)(Khi + base)     = h0;
        *(short8*)(Khi + base + 8) = h1;
        *(short8*)(Klo + base)     = l0;
        *(short8*)(Klo + base + 8) = l1;
    }
    {
        const int sr = t >> 2, dc = (t & 3) << 4;
        #pragma unroll
        for (int u = 0; u < 16; u += 4) {
            f32x4 v = *(const f32x4*)(V + base + u);
            vtile[sr][dc + u + 0] = v[0];
            vtile[sr][dc + u + 1] = v[1];
            vtile[sr][dc + u + 2] = v[2];
            vtile[sr][dc + u + 3] = v[3];
        }
    }
    __syncthreads();
    #pragma unroll
    for (int rep = 0; rep < 16; ++rep) {
        const int idx = rep * 256 + t;
        const int d = idx >> 6, s = idx & 63;
        Vt[((size_t)b * DK + d) * SQ + s0 + s] = (unsigned short)f2bf_u(vtile[s][d]);
    }
}

// ============ prep2: mask bitpack stream + rowsum blocks co-scheduled ============
// blocks [0,16384): bitpack. blocks [16384,18432): rowsum -> I2.
__global__ __launch_bounds__(256) void prep2_kernel(
    const float* __restrict__ Q, const unsigned short* __restrict__ Khi,
    const unsigned short* __restrict__ Klo, const unsigned* __restrict__ Mk,
    unsigned* __restrict__ Mkb, float* __restrict__ I2)
{
    __shared__ float rsum2[4][32];
    const int t = threadIdx.x;

    if (blockIdx.x < 16384) {
        const size_t w = (size_t)blockIdx.x * 256 + t;
        const unsigned* p = Mk + w * 32;
        unsigned bits = 0;
        #pragma unroll
        for (int jj = 0; jj < 8; ++jj) {
            const u32x4 v = *(const u32x4*)(p + jj * 4);
            bits |= (v[0] ? 1u : 0u) << (jj * 4 + 0);
            bits |= (v[1] ? 1u : 0u) << (jj * 4 + 1);
            bits |= (v[2] ? 1u : 0u) << (jj * 4 + 2);
            bits |= (v[3] ? 1u : 0u) << (jj * 4 + 3);
        }
        Mkb[w] = bits;
        return;
    }

    // rowsum block: 256 thr = 4 waves, TQ=32 (dual q-half), wave k-strip = 512
    const int bid2 = blockIdx.x - 16384;          // 0..2047
    const int xcd = bid2 & 7;
    const int j   = bid2 >> 3;                    // 0..255
    const int b   = xcd * 4 + (j >> 6);
    const int q0  = (j & 63) * 32;

    const int lane = t & 63;
    const int wv   = t >> 6;                      // 0..3
    const int m16  = lane & 15;
    const int koff = (lane >> 4) * 8;

    short8 qh0[2], ql0[2], qh1[2], ql1[2];
    {
        const float* qr0 = Q + ((size_t)b * SQ + q0 + m16) * DK;
        split8(qr0 + koff,      qh0[0], ql0[0]);
        split8(qr0 + 32 + koff, qh0[1], ql0[1]);
        const float* qr1 = qr0 + 16 * DK;
        split8(qr1 + koff,      qh1[0], ql1[0]);
        split8(qr1 + 32 + koff, qh1[1], ql1[1]);
    }
    const size_t krow = ((size_t)b * SQ + wv * 512 + m16) * DK;
    const unsigned short* khp = Khi + krow;
    const unsigned short* klp = Klo + krow;

    float rs0 = 0.f, rs1 = 0.f;
    #pragma unroll 8
    for (int tt = 0; tt < 32; ++tt) {
        const int off = tt * 16 * DK;
        const short8 kh0 = *(const short8*)(khp + off + koff);
        const short8 kh1 = *(const short8*)(khp + off + 32 + koff);
        const short8 kl0 = *(const short8*)(klp + off + koff);
        const short8 kl1 = *(const short8*)(klp + off + 32 + koff);
        {
            f32x4 c0 = {0.f,0.f,0.f,0.f}, c1 = {0.f,0.f,0.f,0.f};
            c0 = __builtin_amdgcn_mfma_f32_16x16x32_bf16(kh0, qh0[0], c0, 0, 0, 0);
            c1 = __builtin_amdgcn_mfma_f32_16x16x32_bf16(kh1, qh0[1], c1, 0, 0, 0);
            c0 = __builtin_amdgcn_mfma_f32_16x16x32_bf16(kh0, ql0[0], c0, 0, 0, 0);
            c1 = __builtin_amdgcn_mfma_f32_16x16x32_bf16(kh1, ql0[1], c1, 0, 0, 0);
            c0 = __builtin_amdgcn_mfma_f32_16x16x32_bf16(kl0, qh0[0], c0, 0, 0, 0);
            c1 = __builtin_amdgcn_mfma_f32_16x16x32_bf16(kl1, qh0[1], c1, 0, 0, 0);
            rs0 += (__builtin_amdgcn_exp2f((c0[0]+c1[0])*SCL) + __builtin_amdgcn_exp2f((c0[1]+c1[1])*SCL))
                 + (__builtin_amdgcn_exp2f((c0[2]+c1[2])*SCL) + __builtin_amdgcn_exp2f((c0[3]+c1[3])*SCL));
        }
        {
            f32x4 c0 = {0.f,0.f,0.f,0.f}, c1 = {0.f,0.f,0.f,0.f};
            c0 = __builtin_amdgcn_mfma_f32_16x16x32_bf16(kh0, qh1[0], c0, 0, 0, 0);
            c1 = __builtin_amdgcn_mfma_f32_16x16x32_bf16(kh1, qh1[1], c1, 0, 0, 0);
            c0 = __builtin_amdgcn_mfma_f32_16x16x32_bf16(kh0, ql1[0], c0, 0, 0, 0);
            c1 = __builtin_amdgcn_mfma_f32_16x16x32_bf16(kh1, ql1[1], c1, 0, 0, 0);
            c0 = __builtin_amdgcn_mfma_f32_16x16x32_bf16(kl0, qh1[0], c0, 0, 0, 0);
            c1 = __builtin_amdgcn_mfma_f32_16x16x32_bf16(kl1, qh1[1], c1, 0, 0, 0);
            rs1 += (__builtin_amdgcn_exp2f((c0[0]+c1[0])*SCL) + __builtin_amdgcn_exp2f((c0[1]+c1[1])*SCL))
                 + (__builtin_amdgcn_exp2f((c0[2]+c1[2])*SCL) + __builtin_amdgcn_exp2f((c0[3]+c1[3])*SCL));
        }
    }
    rs0 += __shfl_xor(rs0, 16);  rs0 += __shfl_xor(rs0, 32);
    rs1 += __shfl_xor(rs1, 16);  rs1 += __shfl_xor(rs1, 32);
    if (lane < 16) {
        rsum2[wv][lane]      = rs0;
        rsum2[wv][16 + lane] = rs1;
    }
    __syncthreads();
    if (t < 32) {
        const float s = (rsum2[0][t] + rsum2[1][t]) + (rsum2[2][t] + rsum2[3][t]);
        I2[(size_t)b * SQ + q0 + t] = 2.0f / s;   // includes dropout keep-scale
    }
}

// ============ main: single-phase streaming (i2 known upfront) ============
__global__ __launch_bounds__(512, 4) void sdpa_main(
    const float* __restrict__ Q, const unsigned short* __restrict__ Khi,
    const unsigned short* __restrict__ Klo, const unsigned short* __restrict__ Vt,
    const unsigned* __restrict__ Mkb, const float* __restrict__ I2,
    float* __restrict__ Yout, float* __restrict__ Aout)
{
    __shared__ __align__(16) float astage[8][2][16][36];          // 36.9 KB
    __shared__ __align__(16) unsigned short pstage[8][2][16][36]; // 18.4 KB
    __shared__ float yp[32][68];                                  // 8.7 KB

    const int tid  = threadIdx.x;
    const int lane = tid & 63;
    const int wv   = tid >> 6;          // 0..7; wave k-strip = [wv*256, wv*256+256)
    const int m16  = lane & 15;
    const int kq   = lane >> 4;
    const int koff = kq * 8;

    // XCD batch-affinity swizzle
    const int bx  = blockIdx.x;
    const int xcd = bx & 7;
    const int j   = bx >> 3;            // 0..255
    const int b   = xcd * 4 + (j >> 6);
    const int q0  = (j & 63) * 32;

    // zero y accumulator
    for (int i = tid; i < 32 * 68; i += 512) ((float*)yp)[i] = 0.f;

    // Q fragments, both halves
    short8 qh0[2], ql0[2], qh1[2], ql1[2];
    {
        const float* qr0 = Q + ((size_t)b * SQ + q0 + m16) * DK;
        split8(qr0 + koff,      qh0[0], ql0[0]);
        split8(qr0 + 32 + koff, qh0[1], ql0[1]);
        const float* qr1 = qr0 + 16 * DK;
        split8(qr1 + koff,      qh1[0], ql1[0]);
        split8(qr1 + 32 + koff, qh1[1], ql1[1]);
    }
    const float i2r0 = I2[(size_t)b * SQ + q0 + m16];
    const float i2r1 = I2[(size_t)b * SQ + q0 + 16 + m16];

    const unsigned* mrow0 = Mkb + ((size_t)b * SQ + q0 + m16) * (SQ / 32) + wv * 8;
    const unsigned* mrow1 = mrow0 + (size_t)16 * (SQ / 32);

    const size_t krow = ((size_t)b * SQ + wv * 256 + m16) * DK;
    const unsigned short* khp = Khi + krow;
    const unsigned short* klp = Klo + krow;

    // PV accumulators: A<half><dgroup>
    f32x4 A00={0.f,0.f,0.f,0.f}, A01={0.f,0.f,0.f,0.f}, A02={0.f,0.f,0.f,0.f}, A03={0.f,0.f,0.f,0.f};
    f32x4 A10={0.f,0.f,0.f,0.f}, A11={0.f,0.f,0.f,0.f}, A12={0.f,0.f,0.f,0.f}, A13={0.f,0.f,0.f,0.f};

    __syncthreads();   // yp zero visible before any atomics

    #define QKSTEP(h, s2, K0, K1, L0, L1, QH, QL, I2R, MW)                        \
    {                                                                             \
        f32x4 c0 = {0.f,0.f,0.f,0.f}, c1 = {0.f,0.f,0.f,0.f};                     \
        c0 = __builtin_amdgcn_mfma_f32_16x16x32_bf16(K0, QH[0], c0, 0, 0, 0);     \
        c1 = __builtin_amdgcn_mfma_f32_16x16x32_bf16(K1, QH[1], c1, 0, 0, 0);     \
        c0 = __builtin_amdgcn_mfma_f32_16x16x32_bf16(K0, QL[0], c0, 0, 0, 0);     \
        c1 = __builtin_amdgcn_mfma_f32_16x16x32_bf16(K1, QL[1], c1, 0, 0, 0);     \
        c0 = __builtin_amdgcn_mfma_f32_16x16x32_bf16(L0, QH[0], c0, 0, 0, 0);     \
        c1 = __builtin_amdgcn_mfma_f32_16x16x32_bf16(L1, QH[1], c1, 0, 0, 0);     \
        const float e0 = __builtin_amdgcn_exp2f((c0[0] + c1[0]) * SCL);           \
        const float e1 = __builtin_amdgcn_exp2f((c0[1] + c1[1]) * SCL);           \
        const float e2 = __builtin_amdgcn_exp2f((c0[2] + c1[2]) * SCL);           \
        const float e3 = __builtin_amdgcn_exp2f((c0[3] + c1[3]) * SCL);           \
        const unsigned bits = ((MW) >> ((s2) * 16 + kq * 4)) & 0xfu;              \
        const float p0 = (bits & 1u) ? e0 * (I2R) : 0.f;                          \
        const float p1 = (bits & 2u) ? e1 * (I2R) : 0.f;                          \
        const float p2 = (bits & 4u) ? e2 * (I2R) : 0.f;                          \
        const float p3 = (bits & 8u) ? e3 * (I2R) : 0.f;                          \
        f32x4 pv = {p0, p1, p2, p3};                                              \
        *(f32x4*)&astage[wv][h][m16][(s2) * 16 + kq * 4] = pv;                    \
        u32x2 pk;                                                                 \
        pk[0] = cvtpk_bf16(p0, p1);                                               \
        pk[1] = cvtpk_bf16(p2, p3);                                               \
        *(u32x2*)&pstage[wv][h][m16][(s2) * 16 + kq * 4] = pk;                    \
    }

    #define PVH(h, AA0, AA1, AA2, AA3, kbase)                                     \
    {                                                                             \
        const short8 af = *(const short8*)&pstage[wv][h][m16][koff];              \
        const unsigned short* vb = Vt + ((size_t)b * DK + m16) * SQ + (kbase) + koff; \
        AA0 = __builtin_amdgcn_mfma_f32_16x16x32_bf16(af, *(const short8*)vb, AA0, 0, 0, 0); \
        AA1 = __builtin_amdgcn_mfma_f32_16x16x32_bf16(af, *(const short8*)(vb + (size_t)16 * SQ), AA1, 0, 0, 0); \
        AA2 = __builtin_amdgcn_mfma_f32_16x16x32_bf16(af, *(const short8*)(vb + (size_t)32 * SQ), AA2, 0, 0, 0); \
        AA3 = __builtin_amdgcn_mfma_f32_16x16x32_bf16(af, *(const short8*)(vb + (size_t)48 * SQ), AA3, 0, 0, 0); \
    }

    #define STH(h, kbase)                                                         \
    {                                                                             \
        const int r  = lane >> 2;                                                 \
        const int c8 = (lane & 3) * 8;                                            \
        const f32x4 o0 = *(const f32x4*)&astage[wv][h][r][c8];                    \
        const f32x4 o1 = *(const f32x4*)&astage[wv][h][r][c8 + 4];                \
        float* ap = Aout + ((size_t)b * SQ + q0 + (h) * 16 + r) * SQ + (kbase) + c8; \
        __builtin_nontemporal_store(o0, (f32x4*)ap);                              \
        __builtin_nontemporal_store(o1, (f32x4*)(ap + 4));                        \
    }

    #define PP_ITER(pp)                                                           \
    {                                                                             \
        const int kbase = wv * 256 + (pp) * 32;                                   \
        const int offa = ((pp) * 2) * 16 * DK, offb = ((pp) * 2 + 1) * 16 * DK;   \
        const short8 ka0 = *(const short8*)(khp + offa + koff);                   \
        const short8 ka1 = *(const short8*)(khp + offa + 32 + koff);              \
        const short8 la0 = *(const short8*)(klp + offa + koff);                   \
        const short8 la1 = *(const short8*)(klp + offa + 32 + koff);              \
        const short8 kb0 = *(const short8*)(khp + offb + koff);                   \
        const short8 kb1 = *(const short8*)(khp + offb + 32 + koff);              \
        const short8 lb0 = *(const short8*)(klp + offb + koff);                   \
        const short8 lb1 = *(const short8*)(klp + offb + 32 + koff);              \
        const unsigned mw0 = mrow0[(pp)];                                         \
        const unsigned mw1 = mrow1[(pp)];                                         \
        QKSTEP(0, 0, ka0, ka1, la0, la1, qh0, ql0, i2r0, mw0)                     \
        QKSTEP(0, 1, kb0, kb1, lb0, lb1, qh0, ql0, i2r0, mw0)                     \
        QKSTEP(1, 0, ka0, ka1, la0, la1, qh1, ql1, i2r1, mw1)                     \
        QKSTEP(1, 1, kb0, kb1, lb0, lb1, qh1, ql1, i2r1, mw1)                     \
        PVH(0, A00, A01, A02, A03, kbase)                                         \
        PVH(1, A10, A11, A12, A13, kbase)                                         \
        STH(0, kbase)                                                             \
        STH(1, kbase)                                                             \
    }

    PP_ITER(0) PP_ITER(1) PP_ITER(2) PP_ITER(3)
    PP_ITER(4) PP_ITER(5) PP_ITER(6) PP_ITER(7)

    #undef PP_ITER
    #undef STH
    #undef PVH
    #undef QKSTEP

    // ---- y partial accumulate (LDS atomics), reduce, store ----
    #define YACC(h, g, AC)                                                        \
    {                                                                             \
        _Pragma("unroll")                                                         \
        for (int r = 0; r < 4; ++r)                                               \
            atomicAdd(&yp[(h) * 16 + kq * 4 + r][(g) * 16 + m16], AC[r]);         \
    }
    YACC(0, 0, A00) YACC(0, 1, A01) YACC(0, 2, A02) YACC(0, 3, A03)
    YACC(1, 0, A10) YACC(1, 1, A11) YACC(1, 2, A12) YACC(1, 3, A13)
    #undef YACC
    __syncthreads();

    {
        const int q  = tid >> 4;            // 0..31
        const int d4 = (tid & 15) * 4;      // 0..60
        const f32x4 yv = *(const f32x4*)&yp[q][d4];
        __builtin_nontemporal_store(yv,
            (f32x4*)(Yout + ((size_t)b * SQ + q0 + q) * DK + d4));
    }
}

extern "C" void kernel_launch(void* const* d_in, const int* in_sizes, int n_in,
                              void* d_out, int out_size, void* d_ws, size_t ws_size,
                              hipStream_t stream) {
    const float*    Q  = (const float*)d_in[0];
    const float*    K  = (const float*)d_in[1];
    const float*    V  = (const float*)d_in[2];
    const unsigned* Mk = (const unsigned*)d_in[3];
    float* Yout = (float*)d_out;
    float* Aout = (float*)d_out + (size_t)NB * SQ * DK;

    const size_t NEL = (size_t)NB * SQ * DK;       // 4.19M
    unsigned short* Khi = (unsigned short*)d_ws;
    unsigned short* Klo = Khi + NEL;
    unsigned short* Vt  = Klo + NEL;
    unsigned*       Mkb = (unsigned*)(Vt + NEL);   // NB*SQ*64 words = 16.8 MB
    float*          I2  = (float*)(Mkb + (size_t)NB * SQ * (SQ / 32));

    prep_kernel<<<dim3(NB * 32), dim3(256), 0, stream>>>(K, V, Khi, Klo, Vt);
    prep2_kernel<<<dim3(16384 + 2048), dim3(256), 0, stream>>>(Q, Khi, Klo, Mk, Mkb, I2);
    sdpa_main<<<dim3(NB * (SQ / 32)), dim3(512), 0, stream>>>(
        Q, Khi, Klo, Vt, Mkb, I2, Yout, Aout);
}